// Round 3
// baseline (821.890 us; speedup 1.0000x reference)
//
#include <hip/hip_runtime.h>
#include <hip/hip_bf16.h>

#define NN 512
#define CS 384
#define CZ 128
#define CH 16
#define NH 12
#define PQn 4
#define PVn 8
#define HD 192          // NH*CH
#define QPD 144         // NH*PQn*3
#define VPD 288         // NH*PVn*3
#define PROJW 1152      // HD*3 + QPD*2 + VPD
#define FEAT 2112       // NH*176
#define OUTC 384

// workspace float offsets (total 1,671,168 floats = 6.68 MB)
#define WQO   0
#define WKO   98304
#define WVO   196608
#define WQPO  294912    // local, then rotated in place -> global
#define WKPO  368640
#define WVPO  442368
#define WFEAT 589824    // 512*2112

// K1: all linear projections of s -> fp32 workspace
__global__ __launch_bounds__(256) void proj_kernel(
    const float* __restrict__ s,
    const float* __restrict__ wq, const float* __restrict__ bq,
    const float* __restrict__ wk, const float* __restrict__ bk,
    const float* __restrict__ wv, const float* __restrict__ bv,
    const float* __restrict__ wqp, const float* __restrict__ bqp,
    const float* __restrict__ wkp, const float* __restrict__ bkp,
    const float* __restrict__ wvp, const float* __restrict__ bvp,
    float* __restrict__ ws)
{
    int idx = blockIdx.x * 256 + threadIdx.x;      // N * PROJW
    int n = idx / PROJW, col = idx % PROJW;
    const float *w, *b;
    float* dst; int fan, local;
    if (col < 192)      { local = col;       w = wq;  b = bq;  fan = 192; dst = ws + WQO  + n*192 + local; }
    else if (col < 384) { local = col - 192; w = wk;  b = bk;  fan = 192; dst = ws + WKO  + n*192 + local; }
    else if (col < 576) { local = col - 384; w = wv;  b = bv;  fan = 192; dst = ws + WVO  + n*192 + local; }
    else if (col < 720) { local = col - 576; w = wqp; b = bqp; fan = 144; dst = ws + WQPO + n*144 + local; }
    else if (col < 864) { local = col - 720; w = wkp; b = bkp; fan = 144; dst = ws + WKPO + n*144 + local; }
    else                { local = col - 864; w = wvp; b = bvp; fan = 288; dst = ws + WVPO + n*288 + local; }

    const float* srow = s + n * CS;
    float acc = b[local];
    #pragma unroll 4
    for (int kk = 0; kk < CS; ++kk)
        acc += srow[kk] * w[kk * fan + local];
    *dst = acc;
}

// K2: rotate + translate local points IN PLACE -> global points
__global__ __launch_bounds__(256) void point_global_kernel(
    const float* __restrict__ rot, const float* __restrict__ trans,
    float* __restrict__ ws)
{
    int idx = blockIdx.x * 256 + threadIdx.x;      // N * 192 points
    int n = idx / 192, p = idx % 192;
    float* pt; int off;
    if (p < 48)       { pt = ws + WQPO + n*144; off = p * 3; }
    else if (p < 96)  { pt = ws + WKPO + n*144; off = (p-48) * 3; }
    else              { pt = ws + WVPO + n*288; off = (p-96) * 3; }
    float R[9], T[3];
    #pragma unroll
    for (int i = 0; i < 9; ++i) R[i] = rot[n*9 + i];
    #pragma unroll
    for (int i = 0; i < 3; ++i) T[i] = trans[n*3 + i];
    float x = pt[off], y = pt[off+1], zz = pt[off+2];
    pt[off]   = R[0]*x + R[1]*y + R[2]*zz + T[0];
    pt[off+1] = R[3]*x + R[4]*y + R[5]*zz + T[1];
    pt[off+2] = R[6]*x + R[7]*y + R[8]*zz + T[2];
}

// K3: per-query-row attention: scores (bias fused) + softmax + weighted sums -> features
__global__ __launch_bounds__(256) void attn_kernel(
    const float* __restrict__ ws, const float* __restrict__ z,
    const int* __restrict__ mask,
    const float* __restrict__ rot, const float* __restrict__ trans,
    const float* __restrict__ wb, const float* __restrict__ bb,
    float* __restrict__ feat)
{
    const float* q    = ws + WQO;
    const float* k    = ws + WKO;
    const float* v    = ws + WVO;
    const float* qpg  = ws + WQPO;
    const float* kpg  = ws + WKPO;
    const float* vpg  = ws + WVPO;

    int n = blockIdx.x, tid = threadIdx.x;
    __shared__ float s_w[NN * NH];     // 24576 B: softmax weights
    __shared__ float s_q[HD];
    __shared__ float s_qp[QPD];
    __shared__ float s_wb[CZ * NH];    // 6144 B
    __shared__ float s_bb[NH];
    __shared__ float s_red[4 * NH];
    __shared__ float s_stat[2 * NH];   // [0..11] max, [12..23] sum
    __shared__ float s_pts[VPD];

    for (int i = tid; i < HD;  i += 256) s_q[i]  = q[n*HD + i];
    for (int i = tid; i < QPD; i += 256) s_qp[i] = qpg[n*QPD + i];
    for (int i = tid; i < CZ*NH; i += 256) s_wb[i] = wb[i];
    if (tid < NH) s_bb[tid] = bb[tid];
    int mn = mask[n];
    __syncthreads();

    // phase 1: scores (each thread: m = tid, tid+256), bias fused
    float e[2][NH];
    #pragma unroll
    for (int r = 0; r < 2; ++r) {
        int m = tid + 256 * r;
        const float* kr  = k   + m * HD;
        const float* kpr = kpg + m * QPD;
        const float* zr  = z + ((size_t)n * NN + m) * CZ;
        bool ok = (mn != 0) && (mask[m] != 0);
        float acc[NH];
        #pragma unroll
        for (int h = 0; h < NH; ++h) acc[h] = s_bb[h];
        for (int c = 0; c < CZ; ++c) {
            float zv = zr[c];
            #pragma unroll
            for (int h = 0; h < NH; ++h) acc[h] += zv * s_wb[c*NH + h];
        }
        #pragma unroll
        for (int h = 0; h < NH; ++h) {
            float dot = 0.f;
            #pragma unroll
            for (int c = 0; c < CH; ++c) dot += s_q[h*CH + c] * kr[h*CH + c];
            float pts = 0.f;
            #pragma unroll
            for (int j = 0; j < 12; ++j) { float d = s_qp[h*12 + j] - kpr[h*12 + j]; pts += d * d; }
            float sv = dot * 0.25f - 0.5f * pts + acc[h];
            e[r][h] = ok ? sv : -1e30f;
        }
    }

    int wave = tid >> 6, lane = tid & 63;
    // max reduction
    float mx[NH];
    #pragma unroll
    for (int h = 0; h < NH; ++h) mx[h] = fmaxf(e[0][h], e[1][h]);
    for (int off = 32; off > 0; off >>= 1) {
        #pragma unroll
        for (int h = 0; h < NH; ++h) mx[h] = fmaxf(mx[h], __shfl_xor(mx[h], off, 64));
    }
    if (lane == 0) {
        #pragma unroll
        for (int h = 0; h < NH; ++h) s_red[wave*NH + h] = mx[h];
    }
    __syncthreads();
    if (tid < NH) {
        float m0 = fmaxf(fmaxf(s_red[tid], s_red[NH + tid]),
                         fmaxf(s_red[2*NH + tid], s_red[3*NH + tid]));
        s_stat[tid] = m0;
    }
    __syncthreads();
    // exp + sum reduction
    float sm[NH];
    #pragma unroll
    for (int h = 0; h < NH; ++h) {
        float M = s_stat[h];
        e[0][h] = __expf(e[0][h] - M);
        e[1][h] = __expf(e[1][h] - M);
        sm[h] = e[0][h] + e[1][h];
    }
    for (int off = 32; off > 0; off >>= 1) {
        #pragma unroll
        for (int h = 0; h < NH; ++h) sm[h] += __shfl_xor(sm[h], off, 64);
    }
    if (lane == 0) {
        #pragma unroll
        for (int h = 0; h < NH; ++h) s_red[wave*NH + h] = sm[h];
    }
    __syncthreads();
    if (tid < NH)
        s_stat[NH + tid] = s_red[tid] + s_red[NH + tid] + s_red[2*NH + tid] + s_red[3*NH + tid];
    __syncthreads();
    #pragma unroll
    for (int r = 0; r < 2; ++r) {
        int m = tid + 256 * r;
        #pragma unroll
        for (int h = 0; h < NH; ++h) s_w[m*NH + h] = e[r][h] / s_stat[NH + h];
    }
    __syncthreads();

    float* fout = feat + (size_t)n * FEAT;

    // v_out_scalar: 192 outputs
    for (int o = tid; o < HD; o += 256) {
        int h = o >> 4;
        float acc = 0.f;
        for (int m = 0; m < NN; ++m) acc += s_w[m*NH + h] * v[m*HD + o];
        fout[h*176 + (o & 15)] = acc;
    }
    // v_out_points (global frame): 288 outputs -> LDS
    for (int o = tid; o < VPD; o += 256) {
        int h = o / 24;
        float acc = 0.f;
        for (int m = 0; m < NN; ++m) acc += s_w[m*NH + h] * vpg[m*VPD + o];
        s_pts[o] = acc;
    }
    __syncthreads();
    // local transform + norms
    if (tid < NH * PVn) {
        int h = tid >> 3, p = tid & 7;
        float R[9], T[3];
        #pragma unroll
        for (int i = 0; i < 9; ++i) R[i] = rot[n*9 + i];
        #pragma unroll
        for (int i = 0; i < 3; ++i) T[i] = trans[n*3 + i];
        float x = s_pts[h*24 + p*3]     - T[0];
        float y = s_pts[h*24 + p*3 + 1] - T[1];
        float zz = s_pts[h*24 + p*3 + 2] - T[2];
        float lx = R[0]*x + R[3]*y + R[6]*zz;   // R^T
        float ly = R[1]*x + R[4]*y + R[7]*zz;
        float lz = R[2]*x + R[5]*y + R[8]*zz;
        float* fo = fout + h*176 + 16;
        fo[p*3] = lx; fo[p*3+1] = ly; fo[p*3+2] = lz;
        fout[h*176 + 40 + p] = sqrtf(lx*lx + ly*ly + lz*lz);
    }
    // pair features: thread t -> column c = t&127, heads h0, h0+2, ... (h0 = t>>7)
    {
        int c = tid & 127;
        int h0 = tid >> 7;   // 0 or 1
        float acc[6] = {0.f, 0.f, 0.f, 0.f, 0.f, 0.f};
        const float* zb = z + ((size_t)n * NN) * CZ + c;
        for (int m = 0; m < NN; ++m) {
            float zv = zb[(size_t)m * CZ];
            const float* wr = &s_w[m*NH + h0];
            #pragma unroll
            for (int j = 0; j < 6; ++j) acc[j] += wr[2*j] * zv;
        }
        #pragma unroll
        for (int j = 0; j < 6; ++j) fout[(h0 + 2*j)*176 + 48 + c] = acc[j];
    }
}

// K4: out = features @ wo + bo
__global__ __launch_bounds__(256) void out_kernel(
    const float* __restrict__ feat, const float* __restrict__ wo,
    const float* __restrict__ bo, float* __restrict__ out)
{
    int idx = blockIdx.x * 256 + threadIdx.x;   // N * OUTC
    int n = idx / OUTC, c = idx % OUTC;
    const float* fr = feat + (size_t)n * FEAT;
    float acc = bo[c];
    #pragma unroll 4
    for (int kk = 0; kk < FEAT; ++kk)
        acc += fr[kk] * wo[kk * OUTC + c];
    out[idx] = acc;
}

extern "C" void kernel_launch(void* const* d_in, const int* in_sizes, int n_in,
                              void* d_out, int out_size, void* d_ws, size_t ws_size,
                              hipStream_t stream) {
    (void)in_sizes; (void)n_in; (void)out_size; (void)ws_size;
    const float* s     = (const float*)d_in[0];
    const float* z     = (const float*)d_in[1];
    const float* trans = (const float*)d_in[2];
    const float* rot   = (const float*)d_in[3];
    const int*   mask  = (const int*)d_in[4];
    const float* wq    = (const float*)d_in[5];
    const float* bq    = (const float*)d_in[6];
    const float* wk    = (const float*)d_in[7];
    const float* bk    = (const float*)d_in[8];
    const float* wv    = (const float*)d_in[9];
    const float* bv    = (const float*)d_in[10];
    const float* wqp   = (const float*)d_in[11];
    const float* bqp   = (const float*)d_in[12];
    const float* wkp   = (const float*)d_in[13];
    const float* bkp   = (const float*)d_in[14];
    const float* wvp   = (const float*)d_in[15];
    const float* bvp   = (const float*)d_in[16];
    const float* wb    = (const float*)d_in[17];
    const float* bb    = (const float*)d_in[18];
    const float* wo    = (const float*)d_in[19];
    const float* bo    = (const float*)d_in[20];
    float* ws = (float*)d_ws;
    float* out = (float*)d_out;

    proj_kernel<<<(NN * PROJW) / 256, 256, 0, stream>>>(
        s, wq, bq, wk, bk, wv, bv, wqp, bqp, wkp, bkp, wvp, bvp, ws);
    point_global_kernel<<<(NN * 192) / 256, 256, 0, stream>>>(rot, trans, ws);
    attn_kernel<<<NN, 256, 0, stream>>>(ws, z, mask, rot, trans, wb, bb, ws + WFEAT);
    out_kernel<<<(NN * OUTC) / 256, 256, 0, stream>>>(ws + WFEAT, wo, bo, out);
}

// Round 4
// 612.365 us; speedup vs baseline: 1.3422x; 1.3422x over previous
//
#include <hip/hip_runtime.h>

#define NN 512
#define CS 384
#define CZ 128
#define NH 12
#define PROJW 1152
#define FEAT 2112
#define OUTC 384
#define VPD 288

// workspace float offsets
#define WPROJ 0          // [512][1152]: q 0:192 | k 192:384 | v 384:576 | qp 576:720 | kp 720:864 | vp 864:1152
#define WFEAT 589824     // [512][2112]

// ---------------- K1: proj GEMM (512x1152, K=384) + bias + fused point rotation ----------------
__global__ __launch_bounds__(256) void proj_gemm(
    const float* __restrict__ s,
    const float* __restrict__ wq, const float* __restrict__ bq,
    const float* __restrict__ wk, const float* __restrict__ bk,
    const float* __restrict__ wv, const float* __restrict__ bv,
    const float* __restrict__ wqp, const float* __restrict__ bqp,
    const float* __restrict__ wkp, const float* __restrict__ bkp,
    const float* __restrict__ wvp, const float* __restrict__ bvp,
    const float* __restrict__ rot, const float* __restrict__ trans,
    float* __restrict__ proj)
{
    __shared__ float As[32*68];   // A^T tile: [k][m], stride 68 (16B-aligned rows, conflict-spread)
    __shared__ float Ws[32*52];   // W tile: [k][n], stride 52
    int tid = threadIdx.x;
    int gm0 = blockIdx.x * 64;
    int gc0 = blockIdx.y * 48;
    const float *w, *b; int ldw, lc0;
    if      (gc0 < 192) { w = wq;  b = bq;  ldw = 192; lc0 = gc0;       }
    else if (gc0 < 384) { w = wk;  b = bk;  ldw = 192; lc0 = gc0 - 192; }
    else if (gc0 < 576) { w = wv;  b = bv;  ldw = 192; lc0 = gc0 - 384; }
    else if (gc0 < 720) { w = wqp; b = bqp; ldw = 144; lc0 = gc0 - 576; }
    else if (gc0 < 864) { w = wkp; b = bkp; ldw = 144; lc0 = gc0 - 720; }
    else                { w = wvp; b = bvp; ldw = 288; lc0 = gc0 - 864; }

    int mi = tid >> 4, ni = tid & 15;
    int m0 = mi * 4, n0 = ni * 3;
    float acc[4][3] = {};

    for (int k0 = 0; k0 < CS; k0 += 32) {
        for (int idx = tid; idx < 2048; idx += 256) {
            int r = idx >> 5, c = idx & 31;
            As[c*68 + r] = s[(gm0 + r)*CS + k0 + c];
        }
        for (int idx = tid; idx < 1536; idx += 256) {
            int c = idx / 48, j = idx - c*48;
            Ws[c*52 + j] = w[(k0 + c)*ldw + lc0 + j];
        }
        __syncthreads();
        #pragma unroll 8
        for (int kk = 0; kk < 32; ++kk) {
            float4 a = *(const float4*)&As[kk*68 + m0];
            float w0 = Ws[kk*52 + n0], w1 = Ws[kk*52 + n0 + 1], w2 = Ws[kk*52 + n0 + 2];
            acc[0][0] += a.x*w0; acc[0][1] += a.x*w1; acc[0][2] += a.x*w2;
            acc[1][0] += a.y*w0; acc[1][1] += a.y*w1; acc[1][2] += a.y*w2;
            acc[2][0] += a.z*w0; acc[2][1] += a.z*w1; acc[2][2] += a.z*w2;
            acc[3][0] += a.w*w0; acc[3][1] += a.w*w1; acc[3][2] += a.w*w2;
        }
        __syncthreads();
    }

    float b0 = b[lc0 + n0], b1 = b[lc0 + n0 + 1], b2 = b[lc0 + n0 + 2];
    if (gc0 >= 576) {
        // point segment: n0 is triple-aligned (48%3==0, n0=3*ni); rotate + translate
        #pragma unroll
        for (int i = 0; i < 4; ++i) {
            int gm = gm0 + m0 + i;
            const float* R = rot + gm*9;
            const float* T = trans + gm*3;
            float x = acc[i][0] + b0, y = acc[i][1] + b1, zz = acc[i][2] + b2;
            float gx = R[0]*x + R[1]*y + R[2]*zz + T[0];
            float gy = R[3]*x + R[4]*y + R[5]*zz + T[1];
            float gz = R[6]*x + R[7]*y + R[8]*zz + T[2];
            float* dst = proj + (size_t)gm*PROJW + gc0 + n0;
            dst[0] = gx; dst[1] = gy; dst[2] = gz;
        }
    } else {
        #pragma unroll
        for (int i = 0; i < 4; ++i) {
            float* dst = proj + (size_t)(gm0 + m0 + i)*PROJW + gc0 + n0;
            dst[0] = acc[i][0] + b0; dst[1] = acc[i][1] + b1; dst[2] = acc[i][2] + b2;
        }
    }
}

// ---------------- K2: attention (scores + softmax + weighted sums) ----------------
__global__ __launch_bounds__(256) void attn_kernel(
    const float* __restrict__ proj, const float* __restrict__ z,
    const int* __restrict__ mask,
    const float* __restrict__ wb, const float* __restrict__ bb,
    const float* __restrict__ rot, const float* __restrict__ trans,
    float* __restrict__ feat)
{
    int n = blockIdx.x, tid = threadIdx.x;
    __shared__ float s_sc[NN*13];      // scores -> exp(scores), stride 13 (conflict-free)
    __shared__ float s_red[16*NH];
    __shared__ float s_M[NH], s_S[NH];
    __shared__ float s_pts[VPD];

    const float* qrow  = proj + (size_t)n*PROJW;        // q at 0
    const float* qprow = qrow + 576;                    // qp(global) at 576
    int mn = mask[n];

    // ---- scores (bias fused; wb/q/qp via wave-uniform scalar loads) ----
    for (int r = 0; r < 2; ++r) {
        int m = tid + 256*r;
        const float* krow  = proj + (size_t)m*PROJW + 192;
        const float* kprow = proj + (size_t)m*PROJW + 720;
        const float* zrow  = z + ((size_t)n*NN + m) * CZ;
        bool ok = (mn != 0) && (mask[m] != 0);
        float acc[NH];
        #pragma unroll
        for (int h = 0; h < NH; ++h) acc[h] = bb[h];
        #pragma unroll 4
        for (int c4 = 0; c4 < 32; ++c4) {
            float4 zv = *(const float4*)(zrow + c4*4);
            const float* wbp = wb + c4*48;
            #pragma unroll
            for (int e = 0; e < 4; ++e) {
                float zz = (&zv.x)[e];
                #pragma unroll
                for (int h = 0; h < NH; ++h) acc[h] += zz * wbp[e*12 + h];
            }
        }
        #pragma unroll
        for (int h = 0; h < NH; ++h) {
            const float* qh = qrow + h*16;
            const float* kh = krow + h*16;
            float dot = 0.f;
            #pragma unroll
            for (int c4 = 0; c4 < 4; ++c4) {
                float4 kv = *(const float4*)(kh + c4*4);
                dot += qh[c4*4+0]*kv.x + qh[c4*4+1]*kv.y + qh[c4*4+2]*kv.z + qh[c4*4+3]*kv.w;
            }
            float pts = 0.f;
            const float* qph = qprow + h*12;
            const float* kph = kprow + h*12;
            #pragma unroll
            for (int j = 0; j < 12; ++j) { float d = qph[j] - kph[j]; pts += d*d; }
            float sv = dot*0.25f - 0.5f*pts + acc[h];
            s_sc[m*13 + h] = ok ? sv : -1e30f;
        }
    }
    __syncthreads();

    // ---- softmax: max ----
    if (tid < 192) {
        int i = tid / 12, h = tid - i*12;
        float mx = -1e30f;
        for (int mm = i*32; mm < i*32 + 32; ++mm) mx = fmaxf(mx, s_sc[mm*13 + h]);
        s_red[tid] = mx;
    }
    __syncthreads();
    if (tid < NH) {
        float mx = -1e30f;
        #pragma unroll
        for (int i = 0; i < 16; ++i) mx = fmaxf(mx, s_red[i*12 + tid]);
        s_M[tid] = mx;
    }
    __syncthreads();
    // ---- exp in place ----
    for (int r = 0; r < 2; ++r) {
        int m = tid + 256*r;
        #pragma unroll
        for (int h = 0; h < NH; ++h)
            s_sc[m*13 + h] = __expf(s_sc[m*13 + h] - s_M[h]);
    }
    __syncthreads();
    // ---- sum ----
    if (tid < 192) {
        int i = tid / 12, h = tid - i*12;
        float sm = 0.f;
        for (int mm = i*32; mm < i*32 + 32; ++mm) sm += s_sc[mm*13 + h];
        s_red[tid] = sm;
    }
    __syncthreads();
    if (tid < NH) {
        float sm = 0.f;
        #pragma unroll
        for (int i = 0; i < 16; ++i) sm += s_red[i*12 + tid];
        s_S[tid] = sm;
    }
    __syncthreads();

    float* fout = feat + (size_t)n * FEAT;
    const float* v   = proj + 384;   // column offset within each row
    const float* vpg = proj + 864;

    // ---- v_out_scalar: 192 outputs, coalesced v reads ----
    if (tid < 192) {
        int o = tid, h = o >> 4;
        float acc = 0.f;
        #pragma unroll 4
        for (int m = 0; m < NN; ++m) acc += s_sc[m*13 + h] * v[(size_t)m*PROJW + o];
        fout[h*176 + (o & 15)] = acc / s_S[h];
    }
    // ---- v_out_points (global frame, normalized) -> LDS ----
    for (int o = tid; o < VPD; o += 256) {
        int h = o / 24;
        float acc = 0.f;
        #pragma unroll 4
        for (int m = 0; m < NN; ++m) acc += s_sc[m*13 + h] * vpg[(size_t)m*PROJW + o];
        s_pts[o] = acc / s_S[h];
    }
    __syncthreads();
    // ---- local transform + norms ----
    if (tid < 96) {
        int h = tid >> 3, p = tid & 7;
        const float* R = rot + n*9;
        const float* T = trans + n*3;
        float x  = s_pts[h*24 + p*3]     - T[0];
        float y  = s_pts[h*24 + p*3 + 1] - T[1];
        float zz = s_pts[h*24 + p*3 + 2] - T[2];
        float lx = R[0]*x + R[3]*y + R[6]*zz;   // R^T
        float ly = R[1]*x + R[4]*y + R[7]*zz;
        float lz = R[2]*x + R[5]*y + R[8]*zz;
        float* fo = fout + h*176 + 16;
        fo[p*3] = lx; fo[p*3+1] = ly; fo[p*3+2] = lz;
        fout[h*176 + 40 + p] = sqrtf(lx*lx + ly*ly + lz*lz);
    }
    // ---- pair features: lane=c coalesced z reads ----
    {
        int c = tid & 127, h0 = tid >> 7;
        float pacc[6] = {};
        const float* zb = z + (size_t)n*NN*CZ + c;
        #pragma unroll 4
        for (int m = 0; m < NN; ++m) {
            float zv = zb[(size_t)m*CZ];
            #pragma unroll
            for (int j = 0; j < 6; ++j) pacc[j] += s_sc[m*13 + h0 + 2*j] * zv;
        }
        #pragma unroll
        for (int j = 0; j < 6; ++j) {
            int h = h0 + 2*j;
            fout[h*176 + 48 + c] = pacc[j] / s_S[h];
        }
    }
}

// ---------------- K3: out GEMM (512x384, K=2112), split-K=4, atomic accumulate ----------------
__global__ __launch_bounds__(256) void out_gemm(
    const float* __restrict__ feat, const float* __restrict__ wo,
    const float* __restrict__ bo, float* __restrict__ out)
{
    __shared__ float As[16*68];
    __shared__ float Ws[16*52];
    int tid = threadIdx.x;
    int gm0 = blockIdx.x * 64, gn0 = blockIdx.y * 48;
    int kc = blockIdx.z;              // 0..3, chunks of 528
    int kbase = kc * 528;
    int mi = tid >> 4, ni = tid & 15;
    int m0 = mi * 4, n0 = ni * 3;
    float acc[4][3] = {};

    for (int kt = 0; kt < 33; ++kt) {
        int k0 = kbase + kt*16;
        for (int idx = tid; idx < 1024; idx += 256) {
            int r = idx >> 4, c = idx & 15;
            As[c*68 + r] = feat[(size_t)(gm0 + r)*FEAT + k0 + c];
        }
        for (int idx = tid; idx < 768; idx += 256) {
            int c = idx / 48, j = idx - c*48;
            Ws[c*52 + j] = wo[(size_t)(k0 + c)*OUTC + gn0 + j];
        }
        __syncthreads();
        #pragma unroll 8
        for (int kk = 0; kk < 16; ++kk) {
            float4 a = *(const float4*)&As[kk*68 + m0];
            float w0 = Ws[kk*52 + n0], w1 = Ws[kk*52 + n0 + 1], w2 = Ws[kk*52 + n0 + 2];
            acc[0][0] += a.x*w0; acc[0][1] += a.x*w1; acc[0][2] += a.x*w2;
            acc[1][0] += a.y*w0; acc[1][1] += a.y*w1; acc[1][2] += a.y*w2;
            acc[2][0] += a.z*w0; acc[2][1] += a.z*w1; acc[2][2] += a.z*w2;
            acc[3][0] += a.w*w0; acc[3][1] += a.w*w1; acc[3][2] += a.w*w2;
        }
        __syncthreads();
    }
    #pragma unroll
    for (int i = 0; i < 4; ++i) {
        #pragma unroll
        for (int j = 0; j < 3; ++j) {
            int col = gn0 + n0 + j;
            float val = acc[i][j];
            if (kc == 0) val += bo[col];
            atomicAdd(&out[(size_t)(gm0 + m0 + i)*OUTC + col], val);
        }
    }
}

extern "C" void kernel_launch(void* const* d_in, const int* in_sizes, int n_in,
                              void* d_out, int out_size, void* d_ws, size_t ws_size,
                              hipStream_t stream) {
    (void)in_sizes; (void)n_in; (void)ws_size;
    const float* s     = (const float*)d_in[0];
    const float* z     = (const float*)d_in[1];
    const float* trans = (const float*)d_in[2];
    const float* rot   = (const float*)d_in[3];
    const int*   mask  = (const int*)d_in[4];
    const float* wq    = (const float*)d_in[5];
    const float* bq    = (const float*)d_in[6];
    const float* wk    = (const float*)d_in[7];
    const float* bk    = (const float*)d_in[8];
    const float* wv    = (const float*)d_in[9];
    const float* bv    = (const float*)d_in[10];
    const float* wqp   = (const float*)d_in[11];
    const float* bqp   = (const float*)d_in[12];
    const float* wkp   = (const float*)d_in[13];
    const float* bkp   = (const float*)d_in[14];
    const float* wvp   = (const float*)d_in[15];
    const float* bvp   = (const float*)d_in[16];
    const float* wb    = (const float*)d_in[17];
    const float* bb    = (const float*)d_in[18];
    const float* wo    = (const float*)d_in[19];
    const float* bo    = (const float*)d_in[20];
    float* ws  = (float*)d_ws;
    float* out = (float*)d_out;

    hipMemsetAsync(out, 0, (size_t)out_size * sizeof(float), stream);
    proj_gemm<<<dim3(8, 24), 256, 0, stream>>>(
        s, wq, bq, wk, bk, wv, bv, wqp, bqp, wkp, bkp, wvp, bvp, rot, trans, ws + WPROJ);
    attn_kernel<<<NN, 256, 0, stream>>>(ws + WPROJ, z, mask, wb, bb, rot, trans, ws + WFEAT);
    out_gemm<<<dim3(8, 8, 4), 256, 0, stream>>>(ws + WFEAT, wo, bo, out);
}

// Round 5
// 476.152 us; speedup vs baseline: 1.7261x; 1.2861x over previous
//
#include <hip/hip_runtime.h>

#define NN 512
#define CS 384
#define CZ 128
#define NH 12
#define PROJW 1152
#define FEAT 2112
#define OUTC 384

// workspace float offsets
#define WPROJ 0          // [512][1152]: q 0:192 | k 192:384 | v 384:576 | qp 576:720 | kp 720:864 | vp 864:1152
#define WFEAT 589824     // [512][2112]
#define WOUTP 1671168    // [6][512][384] split-K partials

// ---------------- K1: proj GEMM (512x1152, K=384) + bias + fused point rotation ----------------
__global__ __launch_bounds__(256) void proj_gemm(
    const float* __restrict__ s,
    const float* __restrict__ wq, const float* __restrict__ bq,
    const float* __restrict__ wk, const float* __restrict__ bk,
    const float* __restrict__ wv, const float* __restrict__ bv,
    const float* __restrict__ wqp, const float* __restrict__ bqp,
    const float* __restrict__ wkp, const float* __restrict__ bkp,
    const float* __restrict__ wvp, const float* __restrict__ bvp,
    const float* __restrict__ rot, const float* __restrict__ trans,
    float* __restrict__ proj)
{
    __shared__ float As[32*68];
    __shared__ float Ws[32*52];
    int tid = threadIdx.x;
    int gm0 = blockIdx.x * 64;
    int gc0 = blockIdx.y * 48;
    const float *w, *b; int ldw, lc0;
    if      (gc0 < 192) { w = wq;  b = bq;  ldw = 192; lc0 = gc0;       }
    else if (gc0 < 384) { w = wk;  b = bk;  ldw = 192; lc0 = gc0 - 192; }
    else if (gc0 < 576) { w = wv;  b = bv;  ldw = 192; lc0 = gc0 - 384; }
    else if (gc0 < 720) { w = wqp; b = bqp; ldw = 144; lc0 = gc0 - 576; }
    else if (gc0 < 864) { w = wkp; b = bkp; ldw = 144; lc0 = gc0 - 720; }
    else                { w = wvp; b = bvp; ldw = 288; lc0 = gc0 - 864; }

    int mi = tid >> 4, ni = tid & 15;
    int m0 = mi * 4, n0 = ni * 3;
    float acc[4][3] = {};

    for (int k0 = 0; k0 < CS; k0 += 32) {
        for (int idx = tid; idx < 2048; idx += 256) {
            int r = idx >> 5, c = idx & 31;
            As[c*68 + r] = s[(gm0 + r)*CS + k0 + c];
        }
        for (int idx = tid; idx < 1536; idx += 256) {
            int c = idx / 48, j = idx - c*48;
            Ws[c*52 + j] = w[(k0 + c)*ldw + lc0 + j];
        }
        __syncthreads();
        #pragma unroll 8
        for (int kk = 0; kk < 32; ++kk) {
            float4 a = *(const float4*)&As[kk*68 + m0];
            float w0 = Ws[kk*52 + n0], w1 = Ws[kk*52 + n0 + 1], w2 = Ws[kk*52 + n0 + 2];
            acc[0][0] += a.x*w0; acc[0][1] += a.x*w1; acc[0][2] += a.x*w2;
            acc[1][0] += a.y*w0; acc[1][1] += a.y*w1; acc[1][2] += a.y*w2;
            acc[2][0] += a.z*w0; acc[2][1] += a.z*w1; acc[2][2] += a.z*w2;
            acc[3][0] += a.w*w0; acc[3][1] += a.w*w1; acc[3][2] += a.w*w2;
        }
        __syncthreads();
    }

    float b0 = b[lc0 + n0], b1 = b[lc0 + n0 + 1], b2 = b[lc0 + n0 + 2];
    if (gc0 >= 576) {
        #pragma unroll
        for (int i = 0; i < 4; ++i) {
            int gm = gm0 + m0 + i;
            const float* R = rot + gm*9;
            const float* T = trans + gm*3;
            float x = acc[i][0] + b0, y = acc[i][1] + b1, zz = acc[i][2] + b2;
            float gx = R[0]*x + R[1]*y + R[2]*zz + T[0];
            float gy = R[3]*x + R[4]*y + R[5]*zz + T[1];
            float gz = R[6]*x + R[7]*y + R[8]*zz + T[2];
            float* dst = proj + (size_t)gm*PROJW + gc0 + n0;
            dst[0] = gx; dst[1] = gy; dst[2] = gz;
        }
    } else {
        #pragma unroll
        for (int i = 0; i < 4; ++i) {
            float* dst = proj + (size_t)(gm0 + m0 + i)*PROJW + gc0 + n0;
            dst[0] = acc[i][0] + b0; dst[1] = acc[i][1] + b1; dst[2] = acc[i][2] + b2;
        }
    }
}

// ---------------- K2: attention ----------------
#define WTS 516   // s_wT row stride
__global__ __launch_bounds__(256) void attn_kernel(
    const float* __restrict__ proj, const float* __restrict__ z,
    const int* __restrict__ mask,
    const float* __restrict__ wb, const float* __restrict__ bb,
    const float* __restrict__ rot, const float* __restrict__ trans,
    float* __restrict__ feat)
{
    int n = blockIdx.x, tid = threadIdx.x;
    __shared__ float s_e[NN*16];         // scores -> exp -> normalized w, [m][16]
    __shared__ float s_wT[NH*WTS];       // transposed normalized w, [h][m]
    __shared__ float s_pair[2*NH*128];   // pair partials [mhalf][h][c]
    __shared__ float s_pts[288];
    __shared__ float s_red[16*NH];
    __shared__ float s_M[NH], s_S[NH];

    const float* qrow  = proj + (size_t)n*PROJW;
    const float* qprow = qrow + 576;
    int mn = mask[n];

    // ---- phase A: scores (bias fused) ----
    for (int r = 0; r < 2; ++r) {
        int m = tid + 256*r;
        const float* krow  = proj + (size_t)m*PROJW + 192;
        const float* kprow = proj + (size_t)m*PROJW + 720;
        const float* zrow  = z + ((size_t)n*NN + m) * CZ;
        bool ok = (mn != 0) && (mask[m] != 0);
        float acc[NH];
        #pragma unroll
        for (int h = 0; h < NH; ++h) acc[h] = bb[h];
        #pragma unroll 4
        for (int c4 = 0; c4 < 32; ++c4) {
            float4 zv = *(const float4*)(zrow + c4*4);
            const float* wbp = wb + c4*48;
            #pragma unroll
            for (int e = 0; e < 4; ++e) {
                float zz = (&zv.x)[e];
                #pragma unroll
                for (int h = 0; h < NH; ++h) acc[h] += zz * wbp[e*12 + h];
            }
        }
        float sc[12];
        #pragma unroll
        for (int h = 0; h < NH; ++h) {
            const float* qh = qrow + h*16;
            const float* kh = krow + h*16;
            float dot = 0.f;
            #pragma unroll
            for (int c4 = 0; c4 < 4; ++c4) {
                float4 kv = *(const float4*)(kh + c4*4);
                dot += qh[c4*4+0]*kv.x + qh[c4*4+1]*kv.y + qh[c4*4+2]*kv.z + qh[c4*4+3]*kv.w;
            }
            float pts = 0.f;
            const float* qph = qprow + h*12;
            const float* kph = kprow + h*12;
            #pragma unroll
            for (int j = 0; j < 12; ++j) { float d = qph[j] - kph[j]; pts += d*d; }
            float sv = dot*0.25f - 0.5f*pts + acc[h];
            sc[h] = ok ? sv : -1e30f;
        }
        float* dst = &s_e[m*16];
        *(float4*)(dst)     = make_float4(sc[0], sc[1], sc[2], sc[3]);
        *(float4*)(dst + 4) = make_float4(sc[4], sc[5], sc[6], sc[7]);
        *(float4*)(dst + 8) = make_float4(sc[8], sc[9], sc[10], sc[11]);
    }
    __syncthreads();

    // ---- phase B: max ----
    if (tid < 192) {
        int i = tid / 12, h = tid - i*12;
        float mx = -1e30f;
        for (int mm = i*32; mm < i*32 + 32; ++mm) mx = fmaxf(mx, s_e[mm*16 + h]);
        s_red[tid] = mx;
    }
    __syncthreads();
    if (tid < NH) {
        float mx = -1e30f;
        #pragma unroll
        for (int i = 0; i < 16; ++i) mx = fmaxf(mx, s_red[i*12 + tid]);
        s_M[tid] = mx;
    }
    __syncthreads();
    // ---- phase C: exp in place ----
    {
        float M[12];
        #pragma unroll
        for (int h = 0; h < NH; ++h) M[h] = s_M[h];
        for (int r = 0; r < 2; ++r) {
            int m = tid + 256*r;
            float* row = &s_e[m*16];
            float4 a = *(float4*)row, b4 = *(float4*)(row+4), c4 = *(float4*)(row+8);
            a.x = __expf(a.x - M[0]);  a.y = __expf(a.y - M[1]);
            a.z = __expf(a.z - M[2]);  a.w = __expf(a.w - M[3]);
            b4.x = __expf(b4.x - M[4]); b4.y = __expf(b4.y - M[5]);
            b4.z = __expf(b4.z - M[6]); b4.w = __expf(b4.w - M[7]);
            c4.x = __expf(c4.x - M[8]); c4.y = __expf(c4.y - M[9]);
            c4.z = __expf(c4.z - M[10]); c4.w = __expf(c4.w - M[11]);
            *(float4*)row = a; *(float4*)(row+4) = b4; *(float4*)(row+8) = c4;
        }
    }
    __syncthreads();
    // ---- phase D: sum ----
    if (tid < 192) {
        int i = tid / 12, h = tid - i*12;
        float sm = 0.f;
        for (int mm = i*32; mm < i*32 + 32; ++mm) sm += s_e[mm*16 + h];
        s_red[tid] = sm;
    }
    __syncthreads();
    if (tid < NH) {
        float sm = 0.f;
        #pragma unroll
        for (int i = 0; i < 16; ++i) sm += s_red[i*12 + tid];
        s_S[tid] = sm;
    }
    __syncthreads();
    // ---- phase E: normalize in place + transpose ----
    {
        float iS[12];
        #pragma unroll
        for (int h = 0; h < NH; ++h) iS[h] = 1.0f / s_S[h];
        for (int r = 0; r < 2; ++r) {
            int m = tid + 256*r;
            float* row = &s_e[m*16];
            float4 a = *(float4*)row, b4 = *(float4*)(row+4), c4 = *(float4*)(row+8);
            a.x *= iS[0]; a.y *= iS[1]; a.z *= iS[2]; a.w *= iS[3];
            b4.x *= iS[4]; b4.y *= iS[5]; b4.z *= iS[6]; b4.w *= iS[7];
            c4.x *= iS[8]; c4.y *= iS[9]; c4.z *= iS[10]; c4.w *= iS[11];
            *(float4*)row = a; *(float4*)(row+4) = b4; *(float4*)(row+8) = c4;
            s_wT[0*WTS + m] = a.x;  s_wT[1*WTS + m] = a.y;
            s_wT[2*WTS + m] = a.z;  s_wT[3*WTS + m] = a.w;
            s_wT[4*WTS + m] = b4.x; s_wT[5*WTS + m] = b4.y;
            s_wT[6*WTS + m] = b4.z; s_wT[7*WTS + m] = b4.w;
            s_wT[8*WTS + m] = c4.x; s_wT[9*WTS + m] = c4.y;
            s_wT[10*WTS + m] = c4.z; s_wT[11*WTS + m] = c4.w;
        }
    }
    __syncthreads();

    float* fout = feat + (size_t)n * FEAT;

    // ---- phase F: v_out scalar (192) + points (288), b128 weight reads ----
    for (int rnd = 0; rnd < 2; ++rnd) {
        int o = tid + rnd*256;
        if (o < 480) {
            int col, h; bool isPt = (o >= 192);
            if (!isPt) { col = 384 + o;       h = o >> 4; }
            else       { int p = o - 192; col = 864 + p; h = p / 24; }
            const float* pc = proj + col;
            float acc = 0.f;
            for (int mm = 0; mm < NN; mm += 4) {
                float4 wv = *(const float4*)&s_wT[h*WTS + mm];
                acc += wv.x * pc[(size_t)(mm+0)*PROJW];
                acc += wv.y * pc[(size_t)(mm+1)*PROJW];
                acc += wv.z * pc[(size_t)(mm+2)*PROJW];
                acc += wv.w * pc[(size_t)(mm+3)*PROJW];
            }
            if (!isPt) fout[h*176 + (o & 15)] = acc;
            else       s_pts[o - 192] = acc;
        }
    }
    __syncthreads();
    // ---- phase G: local transform + norms ----
    if (tid < 96) {
        int h = tid >> 3, p = tid & 7;
        const float* R = rot + n*9;
        const float* T = trans + n*3;
        float x  = s_pts[h*24 + p*3]     - T[0];
        float y  = s_pts[h*24 + p*3 + 1] - T[1];
        float zz = s_pts[h*24 + p*3 + 2] - T[2];
        float lx = R[0]*x + R[3]*y + R[6]*zz;
        float ly = R[1]*x + R[4]*y + R[7]*zz;
        float lz = R[2]*x + R[5]*y + R[8]*zz;
        float* fo = fout + h*176 + 16;
        fo[p*3] = lx; fo[p*3+1] = ly; fo[p*3+2] = lz;
        fout[h*176 + 40 + p] = sqrtf(lx*lx + ly*ly + lz*lz);
    }
    // ---- phase H: pair features, m split across wave pairs ----
    {
        int wave = tid >> 6, lane = tid & 63;
        int c = lane + ((wave & 1) << 6);        // 0..127
        int mh = wave >> 1;                      // m half
        const float* zb = z + ((size_t)n*NN + mh*256) * CZ + c;
        float pacc[12] = {};
        for (int mm = 0; mm < 256; ++mm) {
            float zv = zb[(size_t)mm * CZ];
            const float* wr = &s_e[(mh*256 + mm)*16];
            float4 a = *(const float4*)wr, b4 = *(const float4*)(wr+4), c4 = *(const float4*)(wr+8);
            pacc[0] += a.x*zv;  pacc[1] += a.y*zv;  pacc[2] += a.z*zv;  pacc[3] += a.w*zv;
            pacc[4] += b4.x*zv; pacc[5] += b4.y*zv; pacc[6] += b4.z*zv; pacc[7] += b4.w*zv;
            pacc[8] += c4.x*zv; pacc[9] += c4.y*zv; pacc[10] += c4.z*zv; pacc[11] += c4.w*zv;
        }
        #pragma unroll
        for (int h = 0; h < NH; ++h) s_pair[(mh*NH + h)*128 + c] = pacc[h];
    }
    __syncthreads();
    {
        int c = tid & 127, jh = tid >> 7;        // jh: h 0-5 / 6-11
        #pragma unroll
        for (int j = 0; j < 6; ++j) {
            int h = jh*6 + j;
            fout[h*176 + 48 + c] = s_pair[h*128 + c] + s_pair[(NH + h)*128 + c];
        }
    }
}

// ---------------- K3: out GEMM split-K partials (512x384, K=2112, KC=6 x 352) ----------------
__global__ __launch_bounds__(256) void out_gemm(
    const float* __restrict__ feat, const float* __restrict__ wo,
    float* __restrict__ pout)
{
    __shared__ float As[16*68];
    __shared__ float Ws[16*68];
    int tid = threadIdx.x;
    int gm0 = blockIdx.x * 64, gn0 = blockIdx.y * 64;
    int kc = blockIdx.z;
    int kbase = kc * 352;
    int mi = tid >> 4, ni = tid & 15;
    int m0 = mi * 4, n0 = ni * 4;
    float acc[4][4] = {};

    for (int kt = 0; kt < 22; ++kt) {
        int k0 = kbase + kt*16;
        for (int idx = tid; idx < 1024; idx += 256) {
            int r = idx >> 4, c = idx & 15;
            As[c*68 + r] = feat[(size_t)(gm0 + r)*FEAT + k0 + c];
        }
        for (int idx = tid; idx < 1024; idx += 256) {
            int r = idx >> 6, c = idx & 63;
            Ws[r*68 + c] = wo[(size_t)(k0 + r)*OUTC + gn0 + c];
        }
        __syncthreads();
        #pragma unroll 8
        for (int kk = 0; kk < 16; ++kk) {
            float4 a = *(const float4*)&As[kk*68 + m0];
            float4 w = *(const float4*)&Ws[kk*68 + n0];
            acc[0][0] += a.x*w.x; acc[0][1] += a.x*w.y; acc[0][2] += a.x*w.z; acc[0][3] += a.x*w.w;
            acc[1][0] += a.y*w.x; acc[1][1] += a.y*w.y; acc[1][2] += a.y*w.z; acc[1][3] += a.y*w.w;
            acc[2][0] += a.z*w.x; acc[2][1] += a.z*w.y; acc[2][2] += a.z*w.z; acc[2][3] += a.z*w.w;
            acc[3][0] += a.w*w.x; acc[3][1] += a.w*w.y; acc[3][2] += a.w*w.z; acc[3][3] += a.w*w.w;
        }
        __syncthreads();
    }
    float* pb = pout + (size_t)kc * (NN*OUTC);
    #pragma unroll
    for (int i = 0; i < 4; ++i)
        *(float4*)&pb[(size_t)(gm0 + m0 + i)*OUTC + gn0 + n0] =
            make_float4(acc[i][0], acc[i][1], acc[i][2], acc[i][3]);
}

// ---------------- K4: reduce partials + bias ----------------
__global__ __launch_bounds__(256) void out_reduce(
    const float* __restrict__ pout, const float* __restrict__ bo,
    float* __restrict__ out)
{
    int idx4 = blockIdx.x * 256 + threadIdx.x;   // 49152 float4s
    int col4 = idx4 % 96;
    const float4* b4 = (const float4*)bo;
    float4 acc = b4[col4];
    #pragma unroll
    for (int kc = 0; kc < 6; ++kc) {
        float4 p = ((const float4*)(pout + (size_t)kc*(NN*OUTC)))[idx4];
        acc.x += p.x; acc.y += p.y; acc.z += p.z; acc.w += p.w;
    }
    ((float4*)out)[idx4] = acc;
}

extern "C" void kernel_launch(void* const* d_in, const int* in_sizes, int n_in,
                              void* d_out, int out_size, void* d_ws, size_t ws_size,
                              hipStream_t stream) {
    (void)in_sizes; (void)n_in; (void)out_size; (void)ws_size;
    const float* s     = (const float*)d_in[0];
    const float* z     = (const float*)d_in[1];
    const float* trans = (const float*)d_in[2];
    const float* rot   = (const float*)d_in[3];
    const int*   mask  = (const int*)d_in[4];
    const float* wq    = (const float*)d_in[5];
    const float* bq    = (const float*)d_in[6];
    const float* wk    = (const float*)d_in[7];
    const float* bk    = (const float*)d_in[8];
    const float* wv    = (const float*)d_in[9];
    const float* bv    = (const float*)d_in[10];
    const float* wqp   = (const float*)d_in[11];
    const float* bqp   = (const float*)d_in[12];
    const float* wkp   = (const float*)d_in[13];
    const float* bkp   = (const float*)d_in[14];
    const float* wvp   = (const float*)d_in[15];
    const float* bvp   = (const float*)d_in[16];
    const float* wb    = (const float*)d_in[17];
    const float* bb    = (const float*)d_in[18];
    const float* wo    = (const float*)d_in[19];
    const float* bo    = (const float*)d_in[20];
    float* ws  = (float*)d_ws;
    float* out = (float*)d_out;

    proj_gemm<<<dim3(8, 24), 256, 0, stream>>>(
        s, wq, bq, wk, bk, wv, bv, wqp, bqp, wkp, bkp, wvp, bvp, rot, trans, ws + WPROJ);
    attn_kernel<<<NN, 256, 0, stream>>>(ws + WPROJ, z, mask, wb, bb, rot, trans, ws + WFEAT);
    out_gemm<<<dim3(8, 6, 6), 256, 0, stream>>>(ws + WFEAT, wo, ws + WOUTP);
    out_reduce<<<192, 256, 0, stream>>>(ws + WOUTP, bo, out);
}